// Round 9
// baseline (167.606 us; speedup 1.0000x reference)
//
#include <hip/hip_runtime.h>
#include <math.h>

#define N_NODES 80000
#define N_EDGES 1280000
#define D_NODE  128
#define D_EDGE  32
#define D_HID   64
#define NEG_SLOPE 0.2f
#define NB 313              // buckets of 256 target nodes
#define CAP 4608            // slab capacity per bucket (mean 4096 + 8 sigma)
#define EB_BLK 512
#define EB_CHUNK 2048       // edges per chunk
#define EB_NCHUNK (N_EDGES / EB_CHUNK)   // 625, exact

__device__ inline float waveReduceSum(float v) {
    #pragma unroll
    for (int o = 32; o > 0; o >>= 1) v += __shfl_xor(v, o);
    return v;
}
__device__ inline unsigned short f2bf(float f) {   // round-to-nearest-even bf16
    unsigned u = __float_as_uint(f);
    return (unsigned short)((u + 0x7FFF + ((u >> 16) & 1)) >> 16);
}
__device__ inline float bf2f(unsigned short v) {
    return __uint_as_float(((unsigned)v) << 16);
}

// h(bf16) = nf @ W + b; s1 = h . a1; s2 = h . a2 (f32, pre-rounding)
__global__ __launch_bounds__(256) void node_kernel(
        const float* __restrict__ nf, const float* __restrict__ w_w,
        const float* __restrict__ w_b, const float* __restrict__ a_w,
        unsigned short* __restrict__ hb, float* __restrict__ s1, float* __restrict__ s2) {
    __shared__ float Ws[D_HID * D_NODE];   // 32 KB, XOR-swizzled W^T
    __shared__ float Xs[32][D_NODE];       // 16 KB
    for (int i = threadIdx.x; i < D_NODE * D_HID; i += 256) {
        int k = i >> 6, d = i & 63;        // w_w[k][d], row-major [128][64]
        Ws[d * D_NODE + (((k >> 2) ^ (d & 7)) << 2) + (k & 3)] = w_w[i];
    }
    int lane = threadIdx.x & 63;
    int wv   = threadIdx.x >> 6;
    float wb = w_b[lane];
    float a1 = a_w[lane];
    float a2 = a_w[D_HID + lane];
    const float* wrow = &Ws[lane * D_NODE];
    const int nTiles = N_NODES / 32;       // 2500, exact
    for (int tile = blockIdx.x; tile < nTiles; tile += gridDim.x) {
        int n0 = tile * 32;
        __syncthreads();
        {
            const float4* src = (const float4*)(nf + (size_t)n0 * D_NODE);
            float4* dst = (float4*)&Xs[0][0];
            #pragma unroll
            for (int j = 0; j < 4; ++j)
                dst[threadIdx.x + 256 * j] = src[threadIdx.x + 256 * j];
        }
        __syncthreads();
        float acc[8] = {0.f, 0.f, 0.f, 0.f, 0.f, 0.f, 0.f, 0.f};
        const float* xs = &Xs[wv * 8][0];
        #pragma unroll 4
        for (int k4 = 0; k4 < 32; ++k4) {
            float4 w = *(const float4*)&wrow[(k4 ^ (lane & 7)) << 2];
            #pragma unroll
            for (int n = 0; n < 8; ++n) {
                float4 x = *(const float4*)&xs[n * D_NODE + (k4 << 2)];
                acc[n] += w.x * x.x + w.y * x.y + w.z * x.z + w.w * x.w;
            }
        }
        #pragma unroll
        for (int n = 0; n < 8; ++n) {
            int node = n0 + wv * 8 + n;
            float hv = acc[n] + wb;
            hb[(size_t)node * D_HID + lane] = f2bf(hv);
            float r1 = waveReduceSum(hv * a1);
            float r2 = waveReduceSum(hv * a2);
            if (lane == 0) { s1[node] = r1; s2[node] = r2; }
        }
    }
}

// Fused edge partial-score + bucket binning — PURE STREAM, zero scattered reads.
// Dot phase: 4-lane quads per edge -> each ef load instruction covers a
// contiguous 2 KB. Payload q = ef.c + bes; s1[tgt], s2[nbr], leaky, exp are
// all deferred to accum.
__global__ __launch_bounds__(EB_BLK) void edge_bin_kernel(
        const float* __restrict__ ef, const int* __restrict__ eidx,
        const float* __restrict__ ew_w, const float* __restrict__ ew_b,
        const float* __restrict__ a_w, const float* __restrict__ a_b,
        int* __restrict__ bcnt, int2* __restrict__ binned) {
    __shared__ float cs[D_EDGE];
    __shared__ float bes;
    __shared__ int hist[NB], gbase[NB], rank[NB];
    __shared__ float sq [EB_CHUNK];   // 8 KB: q = ef.c + bes
    __shared__ int   stg[EB_CHUNK];   // 8 KB: tgt
    __shared__ int   snb[EB_CHUNK];   // 8 KB: nbr
    int tid = threadIdx.x;
    if (tid < D_EDGE) {
        float s = 0.f;
        #pragma unroll
        for (int d = 0; d < D_HID; ++d) s += ew_w[tid * D_HID + d] * a_w[2 * D_HID + d];
        cs[tid] = s;
    } else if (tid == D_EDGE) {
        float s = 0.f;
        #pragma unroll
        for (int d = 0; d < D_HID; ++d) s += ew_b[d] * a_w[2 * D_HID + d];
        bes = s + a_b[0];
    }
    int qd = tid >> 2;        // 0..127: quad id within block
    int j  = tid & 3;         // lane within quad
    for (int c = blockIdx.x; c < EB_NCHUNK; c += gridDim.x) {
        for (int i = tid; i < NB; i += EB_BLK) { hist[i] = 0; rank[i] = 0; }
        __syncthreads();                       // covers cs/bes on first iter too
        int e0 = c * EB_CHUNK;
        // ---- dot phase: 128 edges per round, 16 rounds ----
        #pragma unroll 2
        for (int rr = 0; rr < EB_CHUNK / 128; ++rr) {
            int idx = rr * 128 + qd;
            int e = e0 + idx;
            const float4* f4 = (const float4*)ef;
            float4 fa = f4[(size_t)e * 8 + j];        // contiguous 2 KB per wave instr
            float4 fb = f4[(size_t)e * 8 + 4 + j];
            const float4 c1 = *(const float4*)&cs[j * 4];
            const float4 c2 = *(const float4*)&cs[16 + j * 4];
            float p = fa.x * c1.x + fa.y * c1.y + fa.z * c1.z + fa.w * c1.w
                    + fb.x * c2.x + fb.y * c2.y + fb.z * c2.z + fb.w * c2.w;
            p += __shfl_xor(p, 1);
            p += __shfl_xor(p, 2);                    // all 4 lanes: full dot
            if (j == 0) {
                int tg = eidx[e];                     // 16 lanes, 64 B contiguous
                sq [idx] = p + bes;
                stg[idx] = tg;
                snb[idx] = eidx[N_EDGES + e];
                atomicAdd(&hist[tg >> 8], 1);
            }
        }
        __syncthreads();
        // ---- reserve dense slab ranges ----
        for (int i = tid; i < NB; i += EB_BLK) {
            int cc = hist[i];
            if (cc) gbase[i] = i * CAP + atomicAdd(&bcnt[i], cc);
        }
        __syncthreads();
        // ---- write phase ----
        #pragma unroll
        for (int k = 0; k < 4; ++k) {
            int idx = k * EB_BLK + tid;
            int tg = stg[idx];
            int b  = tg >> 8;
            int r  = atomicAdd(&rank[b], 1);
            binned[gbase[b] + r] = make_int2(((tg & 255) << 17) | snb[idx],
                                             __float_as_int(sq[idx]));
        }
        __syncthreads();
    }
}

// exclusive scan of 313 bucket counts -> dense bbase[NB+1] + CSR sentinel
__global__ __launch_bounds__(512) void bucket_scan_kernel(
        const int* __restrict__ bcnt, int* __restrict__ bbase,
        int* __restrict__ node_off) {
    __shared__ int buf[512];
    int v = (threadIdx.x < NB) ? bcnt[threadIdx.x] : 0;
    buf[threadIdx.x] = v;
    __syncthreads();
    for (int ofs = 1; ofs < 512; ofs <<= 1) {
        int t = (threadIdx.x >= (unsigned)ofs) ? buf[threadIdx.x - ofs] : 0;
        __syncthreads();
        buf[threadIdx.x] += t;
        __syncthreads();
    }
    if (threadIdx.x < NB) bbase[threadIdx.x] = buf[threadIdx.x] - v;
    if (threadIdx.x == NB - 1) bbase[NB] = buf[threadIdx.x];   // = N_EDGES
    if (threadIdx.x == 0) node_off[N_NODES] = N_EDGES;         // sentinel
}

// one block per bucket: per-node hist + scan + rank in LDS; permute slab
// segment [b*CAP, b*CAP+cnt) into dense CSR pay2 at bbase[b]; emit node_off.
__global__ __launch_bounds__(256) void bucket_csr_kernel(
        const int* __restrict__ bcnt, const int* __restrict__ bbase,
        const int2* __restrict__ binned, int* __restrict__ node_off,
        int2* __restrict__ pay2) {
    __shared__ int nhist[256], buf[256], ncur[256];
    int b = blockIdx.x;
    int in0  = b * CAP;
    int cnt  = bcnt[b];
    int out0 = bbase[b];
    nhist[threadIdx.x] = 0;
    __syncthreads();
    for (int i = threadIdx.x; i < cnt; i += 256)
        atomicAdd(&nhist[binned[in0 + i].x >> 17], 1);
    __syncthreads();
    int v = nhist[threadIdx.x];
    buf[threadIdx.x] = v;
    __syncthreads();
    for (int ofs = 1; ofs < 256; ofs <<= 1) {
        int t = (threadIdx.x >= (unsigned)ofs) ? buf[threadIdx.x - ofs] : 0;
        __syncthreads();
        buf[threadIdx.x] += t;
        __syncthreads();
    }
    int excl = buf[threadIdx.x] - v;
    int n = b * 256 + (int)threadIdx.x;
    if (n < N_NODES) node_off[n] = out0 + excl;
    ncur[threadIdx.x] = excl;
    __syncthreads();
    for (int i = threadIdx.x; i < cnt; i += 256) {
        int2 p = binned[in0 + i];
        int r = atomicAdd(&ncur[p.x >> 17], 1);
        pay2[out0 + r] = make_int2(p.x & 0x1FFFF, p.y);   // {nbr, q bits}
    }
}

// one wave per target node: s = s1[node] (uniform) + q + s2[nbr] (per-lane
// gather, L2-resident 320 KB table); leaky; exp; weighted bf16 h-row gather; elu.
__global__ __launch_bounds__(256) void accum_kernel(
        const int* __restrict__ node_off, const int2* __restrict__ pay2,
        const float* __restrict__ s1, const float* __restrict__ s2v,
        const unsigned short* __restrict__ hb, float* __restrict__ out) {
    __shared__ float exs[4][64];
    __shared__ int   nbs[4][64];
    int wv = threadIdx.x >> 6, lane = threadIdx.x & 63;
    int node = blockIdx.x * 4 + wv;
    if (node >= N_NODES) return;
    int base = node_off[node];
    int cnt  = node_off[node + 1] - base;
    if (cnt == 0) { out[(size_t)node * D_HID + lane] = 0.f; return; }
    float s1i = s1[node];
    float sumex = 0.f, acc = 0.f;
    for (int c0 = 0; c0 < cnt; c0 += 64) {
        int i = c0 + lane;
        int nc = min(64, cnt - c0);
        float exv = 0.f; int nb = 0;
        if (i < cnt) {
            int2 p = pay2[base + i];       // coalesced 8B
            nb = p.x;
            float s = s1i + __int_as_float(p.y) + s2v[nb];
            s = (s > 0.f) ? s : NEG_SLOPE * s;
            exv = __expf(s);               // un-normalized (exp safe in f32)
        }
        sumex += exv;
        exs[wv][lane] = exv;
        nbs[wv][lane] = nb;
        for (int j = 0; j < nc; ++j) {
            acc += exs[wv][j] * bf2f(hb[(size_t)nbs[wv][j] * D_HID + lane]);
        }
    }
    sumex = waveReduceSum(sumex);
    float o = acc / sumex;
    out[(size_t)node * D_HID + lane] = (o > 0.f) ? o : (__expf(o) - 1.f);
}

extern "C" void kernel_launch(void* const* d_in, const int* in_sizes, int n_in,
                              void* d_out, int out_size, void* d_ws, size_t ws_size,
                              hipStream_t stream) {
    const float* nf   = (const float*)d_in[0];
    const float* ef   = (const float*)d_in[1];
    const int*   eidx = (const int*)d_in[2];
    const float* w_w  = (const float*)d_in[3];
    const float* w_b  = (const float*)d_in[4];
    const float* ew_w = (const float*)d_in[5];
    const float* ew_b = (const float*)d_in[6];
    const float* a_w  = (const float*)d_in[7];
    const float* a_b  = (const float*)d_in[8];
    float* out = (float*)d_out;

    char* ws = (char*)d_ws;
    size_t o = 0;
    auto alloc = [&](size_t bytes) -> void* {
        void* p = ws + o;
        o = (o + bytes + 255) & ~(size_t)255;
        return p;
    };
    unsigned short* hb  = (unsigned short*)alloc((size_t)N_NODES * D_HID * 2);
    float* s1       = (float*)alloc((size_t)N_NODES * 4);
    float* s2       = (float*)alloc((size_t)N_NODES * 4);
    int*   bcnt     = (int*)alloc((size_t)NB * 4);
    int*   bbase    = (int*)alloc((size_t)(NB + 1) * 4);
    int*   node_off = (int*)alloc((size_t)(N_NODES + 1) * 4);
    int2*  binned   = (int2*)alloc((size_t)NB * CAP * 8);
    int2*  pay2     = (int2*)alloc((size_t)N_EDGES * 8);

    hipMemsetAsync(bcnt, 0, (size_t)NB * 4, stream);

    node_kernel<<<1250, 256, 0, stream>>>(nf, w_w, w_b, a_w, hb, s1, s2);
    edge_bin_kernel<<<EB_NCHUNK, EB_BLK, 0, stream>>>(ef, eidx, ew_w, ew_b, a_w, a_b, bcnt, binned);
    bucket_scan_kernel<<<1, 512, 0, stream>>>(bcnt, bbase, node_off);
    bucket_csr_kernel<<<NB, 256, 0, stream>>>(bcnt, bbase, binned, node_off, pay2);
    accum_kernel<<<(N_NODES + 3) / 4, 256, 0, stream>>>(node_off, pay2, s1, s2, hb, out);
}

// Round 10
// 163.513 us; speedup vs baseline: 1.0250x; 1.0250x over previous
//
#include <hip/hip_runtime.h>
#include <math.h>

#define N_NODES 80000
#define N_EDGES 1280000
#define D_NODE  128
#define D_EDGE  32
#define D_HID   64
#define NEG_SLOPE 0.2f
#define NB 313              // buckets of 256 target nodes
#define CAP 4608            // slab capacity per bucket (mean 4096 + 8 sigma)
#define EB_BLK 512
#define EB_CHUNK 2048       // edges per chunk
#define EB_NCHUNK (N_EDGES / EB_CHUNK)   // 625, exact

__device__ inline float waveReduceSum(float v) {
    #pragma unroll
    for (int o = 32; o > 0; o >>= 1) v += __shfl_xor(v, o);
    return v;
}
__device__ inline unsigned short f2bf(float f) {   // round-to-nearest-even bf16
    unsigned u = __float_as_uint(f);
    return (unsigned short)((u + 0x7FFF + ((u >> 16) & 1)) >> 16);
}
__device__ inline float bf2f(unsigned short v) {
    return __uint_as_float(((unsigned)v) << 16);
}

// h(bf16) = nf @ W + b; s1 = h . a1; s2 = h . a2 (f32, pre-rounding)
__global__ __launch_bounds__(256) void node_kernel(
        const float* __restrict__ nf, const float* __restrict__ w_w,
        const float* __restrict__ w_b, const float* __restrict__ a_w,
        unsigned short* __restrict__ hb, float* __restrict__ s1, float* __restrict__ s2) {
    __shared__ float Ws[D_HID * D_NODE];   // 32 KB, XOR-swizzled W^T
    __shared__ float Xs[32][D_NODE];       // 16 KB
    for (int i = threadIdx.x; i < D_NODE * D_HID; i += 256) {
        int k = i >> 6, d = i & 63;        // w_w[k][d], row-major [128][64]
        Ws[d * D_NODE + (((k >> 2) ^ (d & 7)) << 2) + (k & 3)] = w_w[i];
    }
    int lane = threadIdx.x & 63;
    int wv   = threadIdx.x >> 6;
    float wb = w_b[lane];
    float a1 = a_w[lane];
    float a2 = a_w[D_HID + lane];
    const float* wrow = &Ws[lane * D_NODE];
    const int nTiles = N_NODES / 32;       // 2500, exact
    for (int tile = blockIdx.x; tile < nTiles; tile += gridDim.x) {
        int n0 = tile * 32;
        __syncthreads();
        {
            const float4* src = (const float4*)(nf + (size_t)n0 * D_NODE);
            float4* dst = (float4*)&Xs[0][0];
            #pragma unroll
            for (int j = 0; j < 4; ++j)
                dst[threadIdx.x + 256 * j] = src[threadIdx.x + 256 * j];
        }
        __syncthreads();
        float acc[8] = {0.f, 0.f, 0.f, 0.f, 0.f, 0.f, 0.f, 0.f};
        const float* xs = &Xs[wv * 8][0];
        #pragma unroll 4
        for (int k4 = 0; k4 < 32; ++k4) {
            float4 w = *(const float4*)&wrow[(k4 ^ (lane & 7)) << 2];
            #pragma unroll
            for (int n = 0; n < 8; ++n) {
                float4 x = *(const float4*)&xs[n * D_NODE + (k4 << 2)];
                acc[n] += w.x * x.x + w.y * x.y + w.z * x.z + w.w * x.w;
            }
        }
        #pragma unroll
        for (int n = 0; n < 8; ++n) {
            int node = n0 + wv * 8 + n;
            float hv = acc[n] + wb;
            hb[(size_t)node * D_HID + lane] = f2bf(hv);
            float r1 = waveReduceSum(hv * a1);
            float r2 = waveReduceSum(hv * a2);
            if (lane == 0) { s1[node] = r1; s2[node] = r2; }
        }
    }
}

// Fused edge partial-score + bucket binning, issue-balanced.
// Phase A: ALL 512 threads (4 edges each) do the coalesced eidx loads, the
//   s2[nbr] gather (full-wave issue parallelism), sq = bes + s2, hist atomics.
// Phase B: pure ef stream via 4-lane quads (each load instr covers a
//   contiguous 2 KB); quad-reduce dot added into sq.
// Phase C/D: reserve dense slab ranges, write binned (full-line runs).
// Payload q = ef.c + bes + s2[nbr]; s1[tgt] + leaky + exp deferred to accum.
__global__ __launch_bounds__(EB_BLK) void edge_bin_kernel(
        const float* __restrict__ ef, const int* __restrict__ eidx,
        const float* __restrict__ s2v,
        const float* __restrict__ ew_w, const float* __restrict__ ew_b,
        const float* __restrict__ a_w, const float* __restrict__ a_b,
        int* __restrict__ bcnt, int2* __restrict__ binned) {
    __shared__ float cs[D_EDGE];
    __shared__ float bes;
    __shared__ int hist[NB], gbase[NB], rank[NB];
    __shared__ float sq [EB_CHUNK];   // 8 KB: bes + s2[nbr], then += ef.c
    __shared__ int   stg[EB_CHUNK];   // 8 KB: tgt
    __shared__ int   snb[EB_CHUNK];   // 8 KB: nbr
    int tid = threadIdx.x;
    if (tid < D_EDGE) {
        float s = 0.f;
        #pragma unroll
        for (int d = 0; d < D_HID; ++d) s += ew_w[tid * D_HID + d] * a_w[2 * D_HID + d];
        cs[tid] = s;
    } else if (tid == D_EDGE) {
        float s = 0.f;
        #pragma unroll
        for (int d = 0; d < D_HID; ++d) s += ew_b[d] * a_w[2 * D_HID + d];
        bes = s + a_b[0];
    }
    int qd = tid >> 2;        // 0..127: quad id within block
    int j  = tid & 3;         // lane within quad
    for (int c = blockIdx.x; c < EB_NCHUNK; c += gridDim.x) {
        for (int i = tid; i < NB; i += EB_BLK) { hist[i] = 0; rank[i] = 0; }
        __syncthreads();                       // covers cs/bes on first iter too
        int e0 = c * EB_CHUNK;
        // ---- Phase A: index loads + s2 gather + hist, full-lane issue ----
        #pragma unroll
        for (int k = 0; k < 4; ++k) {
            int idx = k * EB_BLK + tid;
            int e = e0 + idx;                  // coalesced 2 KB per wave instr
            int tg = eidx[e];
            int nb = eidx[N_EDGES + e];
            stg[idx] = tg;
            snb[idx] = nb;
            sq [idx] = bes + s2v[nb];          // gather issued by all 64 lanes
            atomicAdd(&hist[tg >> 8], 1);
        }
        __syncthreads();
        // ---- Phase B: ef stream dot, 128 edges per round ----
        #pragma unroll 2
        for (int rr = 0; rr < EB_CHUNK / 128; ++rr) {
            int idx = rr * 128 + qd;
            int e = e0 + idx;
            const float4* f4 = (const float4*)ef;
            float4 fa = f4[(size_t)e * 8 + j];        // contiguous 2 KB per wave instr
            float4 fb = f4[(size_t)e * 8 + 4 + j];
            const float4 c1 = *(const float4*)&cs[j * 4];
            const float4 c2 = *(const float4*)&cs[16 + j * 4];
            float p = fa.x * c1.x + fa.y * c1.y + fa.z * c1.z + fa.w * c1.w
                    + fb.x * c2.x + fb.y * c2.y + fb.z * c2.z + fb.w * c2.w;
            p += __shfl_xor(p, 1);
            p += __shfl_xor(p, 2);                    // all 4 lanes: full dot
            if (j == 0) sq[idx] += p;                 // one writer per idx
        }
        __syncthreads();
        // ---- Phase C: reserve dense slab ranges ----
        for (int i = tid; i < NB; i += EB_BLK) {
            int cc = hist[i];
            if (cc) gbase[i] = i * CAP + atomicAdd(&bcnt[i], cc);
        }
        __syncthreads();
        // ---- Phase D: write ----
        #pragma unroll
        for (int k = 0; k < 4; ++k) {
            int idx = k * EB_BLK + tid;
            int tg = stg[idx];
            int b  = tg >> 8;
            int r  = atomicAdd(&rank[b], 1);
            binned[gbase[b] + r] = make_int2(((tg & 255) << 17) | snb[idx],
                                             __float_as_int(sq[idx]));
        }
        __syncthreads();
    }
}

// exclusive scan of 313 bucket counts -> dense bbase[NB+1] + CSR sentinel
__global__ __launch_bounds__(512) void bucket_scan_kernel(
        const int* __restrict__ bcnt, int* __restrict__ bbase,
        int* __restrict__ node_off) {
    __shared__ int buf[512];
    int v = (threadIdx.x < NB) ? bcnt[threadIdx.x] : 0;
    buf[threadIdx.x] = v;
    __syncthreads();
    for (int ofs = 1; ofs < 512; ofs <<= 1) {
        int t = (threadIdx.x >= (unsigned)ofs) ? buf[threadIdx.x - ofs] : 0;
        __syncthreads();
        buf[threadIdx.x] += t;
        __syncthreads();
    }
    if (threadIdx.x < NB) bbase[threadIdx.x] = buf[threadIdx.x] - v;
    if (threadIdx.x == NB - 1) bbase[NB] = buf[threadIdx.x];   // = N_EDGES
    if (threadIdx.x == 0) node_off[N_NODES] = N_EDGES;         // sentinel
}

// one block per bucket: per-node hist + scan + rank in LDS; permute slab
// segment [b*CAP, b*CAP+cnt) into dense CSR pay2 at bbase[b]; emit node_off.
__global__ __launch_bounds__(256) void bucket_csr_kernel(
        const int* __restrict__ bcnt, const int* __restrict__ bbase,
        const int2* __restrict__ binned, int* __restrict__ node_off,
        int2* __restrict__ pay2) {
    __shared__ int nhist[256], buf[256], ncur[256];
    int b = blockIdx.x;
    int in0  = b * CAP;
    int cnt  = bcnt[b];
    int out0 = bbase[b];
    nhist[threadIdx.x] = 0;
    __syncthreads();
    for (int i = threadIdx.x; i < cnt; i += 256)
        atomicAdd(&nhist[binned[in0 + i].x >> 17], 1);
    __syncthreads();
    int v = nhist[threadIdx.x];
    buf[threadIdx.x] = v;
    __syncthreads();
    for (int ofs = 1; ofs < 256; ofs <<= 1) {
        int t = (threadIdx.x >= (unsigned)ofs) ? buf[threadIdx.x - ofs] : 0;
        __syncthreads();
        buf[threadIdx.x] += t;
        __syncthreads();
    }
    int excl = buf[threadIdx.x] - v;
    int n = b * 256 + (int)threadIdx.x;
    if (n < N_NODES) node_off[n] = out0 + excl;
    ncur[threadIdx.x] = excl;
    __syncthreads();
    for (int i = threadIdx.x; i < cnt; i += 256) {
        int2 p = binned[in0 + i];
        int r = atomicAdd(&ncur[p.x >> 17], 1);
        pay2[out0 + r] = make_int2(p.x & 0x1FFFF, p.y);   // {nbr, q bits}
    }
}

// one wave per target node: s = s1[node] (uniform) + q; leaky; exp; weighted
// bf16 h-row gather; elu. (q already contains ef.c + bes + s2[nbr].)
__global__ __launch_bounds__(256) void accum_kernel(
        const int* __restrict__ node_off, const int2* __restrict__ pay2,
        const float* __restrict__ s1, const unsigned short* __restrict__ hb,
        float* __restrict__ out) {
    __shared__ float exs[4][64];
    __shared__ int   nbs[4][64];
    int wv = threadIdx.x >> 6, lane = threadIdx.x & 63;
    int node = blockIdx.x * 4 + wv;
    if (node >= N_NODES) return;
    int base = node_off[node];
    int cnt  = node_off[node + 1] - base;
    if (cnt == 0) { out[(size_t)node * D_HID + lane] = 0.f; return; }
    float s1i = s1[node];
    float sumex = 0.f, acc = 0.f;
    for (int c0 = 0; c0 < cnt; c0 += 64) {
        int i = c0 + lane;
        int nc = min(64, cnt - c0);
        float exv = 0.f; int nb = 0;
        if (i < cnt) {
            int2 p = pay2[base + i];       // coalesced 8B
            nb = p.x;
            float s = s1i + __int_as_float(p.y);
            s = (s > 0.f) ? s : NEG_SLOPE * s;
            exv = __expf(s);               // un-normalized (exp safe in f32)
        }
        sumex += exv;
        exs[wv][lane] = exv;
        nbs[wv][lane] = nb;
        for (int j = 0; j < nc; ++j) {
            acc += exs[wv][j] * bf2f(hb[(size_t)nbs[wv][j] * D_HID + lane]);
        }
    }
    sumex = waveReduceSum(sumex);
    float o = acc / sumex;
    out[(size_t)node * D_HID + lane] = (o > 0.f) ? o : (__expf(o) - 1.f);
}

extern "C" void kernel_launch(void* const* d_in, const int* in_sizes, int n_in,
                              void* d_out, int out_size, void* d_ws, size_t ws_size,
                              hipStream_t stream) {
    const float* nf   = (const float*)d_in[0];
    const float* ef   = (const float*)d_in[1];
    const int*   eidx = (const int*)d_in[2];
    const float* w_w  = (const float*)d_in[3];
    const float* w_b  = (const float*)d_in[4];
    const float* ew_w = (const float*)d_in[5];
    const float* ew_b = (const float*)d_in[6];
    const float* a_w  = (const float*)d_in[7];
    const float* a_b  = (const float*)d_in[8];
    float* out = (float*)d_out;

    char* ws = (char*)d_ws;
    size_t o = 0;
    auto alloc = [&](size_t bytes) -> void* {
        void* p = ws + o;
        o = (o + bytes + 255) & ~(size_t)255;
        return p;
    };
    unsigned short* hb  = (unsigned short*)alloc((size_t)N_NODES * D_HID * 2);
    float* s1       = (float*)alloc((size_t)N_NODES * 4);
    float* s2       = (float*)alloc((size_t)N_NODES * 4);
    int*   bcnt     = (int*)alloc((size_t)NB * 4);
    int*   bbase    = (int*)alloc((size_t)(NB + 1) * 4);
    int*   node_off = (int*)alloc((size_t)(N_NODES + 1) * 4);
    int2*  binned   = (int2*)alloc((size_t)NB * CAP * 8);
    int2*  pay2     = (int2*)alloc((size_t)N_EDGES * 8);

    hipMemsetAsync(bcnt, 0, (size_t)NB * 4, stream);

    node_kernel<<<1250, 256, 0, stream>>>(nf, w_w, w_b, a_w, hb, s1, s2);
    edge_bin_kernel<<<EB_NCHUNK, EB_BLK, 0, stream>>>(ef, eidx, s2, ew_w, ew_b, a_w, a_b, bcnt, binned);
    bucket_scan_kernel<<<1, 512, 0, stream>>>(bcnt, bbase, node_off);
    bucket_csr_kernel<<<NB, 256, 0, stream>>>(bcnt, bbase, binned, node_off, pay2);
    accum_kernel<<<(N_NODES + 3) / 4, 256, 0, stream>>>(node_off, pay2, s1, hb, out);
}